// Round 10
// baseline (327.434 us; speedup 1.0000x reference)
//
#include <hip/hip_runtime.h>
#include <stdint.h>

#define C_IN 128
#define NUMD 524288
#define LNUMD 32768
#define NNUM_DM1 (LNUMD + NUMD/8)
#define PREFIX 16384
#define N_CONV (PREFIX + NNUM_DM1)   // 114688
#define N_EDGES (N_CONV * 7)         // 802816
#define ND8 (NUMD/8)                 // 65536
#define CAP 32
#define EG 12

#define COPY_BLK ((PREFIX+LNUMD)*32/256)     // 6144
#define PREPW_N (114688 + 6272 + 131072)     // w16y + wbias + wd16 = 252032
#define PREPW_BLK ((PREPW_N + 255)/256)      // 985
#define ZERO_BLK 137                         // (cnt 114688 + bitmap 25600) int4-strided
#define DOWN_BLK (ND8/128)                   // 512
#define SCAT_BLK (N_EDGES/512)               // 1568

typedef __attribute__((ext_vector_type(8))) short short8;
typedef __attribute__((ext_vector_type(4))) float f32x4;

__device__ inline ushort f2b(float f){
  union { float f; uint32_t u; } v; v.f = f;
  uint32_t r = v.u + 0x7fffu + ((v.u >> 16) & 1u);
  return (ushort)(r >> 16);
}
__device__ inline float b2f_lo(uint32_t u){ union { uint32_t u; float f; } v; v.u = u << 16; return v.f; }
__device__ inline float b2f_hi(uint32_t u){ union { uint32_t u; float f; } v; v.u = u & 0xffff0000u; return v.f; }

#define BAR_LGKM() do { \
    asm volatile("s_waitcnt lgkmcnt(0)" ::: "memory"); \
    __builtin_amdgcn_s_barrier(); \
    asm volatile("" ::: "memory"); \
  } while(0)

// ---- fused: copy prefix+leaf rows | weight conversion | zero cnt+bitmap ----
__global__ void k_prep(const float* __restrict__ x, const float* __restrict__ wconv,
                       const float* __restrict__ wdown,
                       ushort* __restrict__ xconv, ushort* __restrict__ w16y,
                       ushort* __restrict__ wbias, ushort* __restrict__ wd16,
                       int* __restrict__ cnt){
  const int bid = blockIdx.x;
  if (bid < COPY_BLK){
    int gid = bid*256 + threadIdx.x;
    int row = gid >> 5, seg = (gid & 31) * 4;
    int srow, drow;
    if (row < PREFIX){ srow = row; drow = row; }
    else { int k = row - PREFIX; srow = PREFIX + k; drow = PREFIX + 3*k; }
    const float4 f = *(const float4*)(x + (size_t)srow*C_IN + seg);
    ushort4 o; o.x=f2b(f.x); o.y=f2b(f.y); o.z=f2b(f.z); o.w=f2b(f.w);
    *(ushort4*)(xconv + (size_t)drow*C_IN + seg) = o;
  } else if (bid < COPY_BLK + PREPW_BLK){
    int gid = (bid - COPY_BLK)*256 + threadIdx.x;
    if (gid < 114688){
      // w16y[t][o][k] = wconv[(t*135+k)*128 + o]
      int t = gid >> 14, rem = gid & 16383;
      int o = rem >> 7, k = rem & 127;
      w16y[gid] = f2b(wconv[(size_t)(t*135 + k)*128 + o]);
    } else if (gid < 120960){
      // wbias[t][n][o] = wconv[(t*135+128+n)*128 + o]
      int q = gid - 114688;
      int t = q / 896, rem = q % 896;
      int n = rem >> 7, o = rem & 127;
      wbias[q] = f2b(wconv[(size_t)(t*135 + 128 + n)*128 + o]);
    } else if (gid < PREPW_N){
      int i = gid - 120960;
      wd16[i] = f2b(wdown[i]);
    }
  } else {
    // zero cnt[114688] + bitmap[25600] (contiguous)
    int gid = (bid - COPY_BLK - PREPW_BLK)*256 + threadIdx.x;
    int4 z = {0,0,0,0};
    *(int4*)(cnt + gid*4) = z;
  }
}

// ---- fused: down-projection GEMM (128-row tile, K-chunked) | edge scatter ----
__global__ __launch_bounds__(512) void k_sd(const int* __restrict__ ei, const int* __restrict__ et,
    int* __restrict__ cnt, int* __restrict__ bucket, uint* __restrict__ bitmap,
    const float* __restrict__ x, const ushort* __restrict__ wd16, ushort* __restrict__ xconv){
  const int bid = blockIdx.x;
  if (bid >= DOWN_BLK){
    int e = (bid - DOWN_BLK)*512 + threadIdx.x;
    int r = ei[e], c = ei[N_EDGES + e], t = et[e];
    int key = c*7 + t;
    int pos = atomicAdd(&cnt[r], 1);
    if (pos < CAP) bucket[r*CAP + pos] = key;
    atomicOr(&bitmap[key >> 5], 1u << (key & 31));
    return;
  }
  __shared__ ushort As[128*128];      // row*128 + (slot ^ ((row&7)<<1))*8
  const int tid = threadIdx.x;
  const int n0 = bid * 128;
  const float* xd = x + (size_t)(PREFIX+LNUMD)*C_IN;

  const int srow = tid >> 2, kbase = (tid & 3) * 32;
  const float* src = xd + (size_t)(n0+srow)*1024 + kbase;

  const int w = tid >> 6, l = tid & 63;
  const int mg = w >> 2, nc = w & 3;            // 2 row-groups x 4 col-groups
  const int arow = l & 15, kgrp = l >> 4;
  const int obase = nc*32 + arow;

  f32x4 acc[4][2];
  #pragma unroll
  for (int mf=0;mf<4;mf++){ acc[mf][0]=(f32x4){0,0,0,0}; acc[mf][1]=(f32x4){0,0,0,0}; }

  float4 pf[8];
  #pragma unroll
  for (int i=0;i<8;i++) pf[i] = *(const float4*)(src + i*4);

  for (int c = 0; c < 8; ++c){
    // pack prefetched A -> LDS (swizzled)
    #pragma unroll
    for (int i=0;i<4;i++){
      uint4 pk;
      pk.x = (uint)f2b(pf[2*i].x)   | ((uint)f2b(pf[2*i].y)<<16);
      pk.y = (uint)f2b(pf[2*i].z)   | ((uint)f2b(pf[2*i].w)<<16);
      pk.z = (uint)f2b(pf[2*i+1].x) | ((uint)f2b(pf[2*i+1].y)<<16);
      pk.w = (uint)f2b(pf[2*i+1].z) | ((uint)f2b(pf[2*i+1].w)<<16);
      int slot = (kbase >> 3) + i;
      *(uint4*)&As[srow*128 + ((slot ^ ((srow & 7) << 1)) << 3)] = pk;
    }
    BAR_LGKM();                                 // LDS visible; vmcnt untouched

    // B fragments for this chunk -> registers FIRST (oldest in vmcnt FIFO, L2-hot)
    short8 breg[8];
    #pragma unroll
    for (int kf=0;kf<4;kf++){
      const ushort* bp = wd16 + c*128 + kf*32 + kgrp*8;
      breg[kf*2]   = *(const short8*)(bp + (size_t)obase*1024);
      breg[kf*2+1] = *(const short8*)(bp + (size_t)(obase+16)*1024);
    }
    // THEN issue next chunk's A prefetch (youngest: stays in flight over MFMA)
    if (c < 7){
      const float* s2 = src + (c+1)*128;
      #pragma unroll
      for (int i=0;i<8;i++) pf[i] = *(const float4*)(s2 + i*4);
    }

    // MFMA from LDS A + reg B
    #pragma unroll
    for (int kf=0;kf<4;kf++){
      #pragma unroll
      for (int mf=0;mf<4;mf++){
        int row = mg*64 + mf*16 + arow;
        int slot = (kf*4 + kgrp) ^ ((arow & 7) << 1);
        short8 a = *(const short8*)&As[row*128 + (slot << 3)];
        acc[mf][0] = __builtin_amdgcn_mfma_f32_16x16x32_bf16(a, breg[kf*2],   acc[mf][0], 0,0,0);
        acc[mf][1] = __builtin_amdgcn_mfma_f32_16x16x32_bf16(a, breg[kf*2+1], acc[mf][1], 0,0,0);
      }
    }
    BAR_LGKM();                                 // protect As before next ds_write
  }

  #pragma unroll
  for (int mf = 0; mf < 4; ++mf){
    #pragma unroll
    for (int j = 0; j < 4; ++j){
      int rl = mg*64 + mf*16 + (l>>4)*4 + j;
      int n = n0 + rl;
      int i = 3*(n>>1) + 1 + (n&1);
      ushort* dst = xconv + (size_t)(PREFIX + i)*C_IN;
      dst[obase]      = f2b(acc[mf][0][j]);
      dst[obase + 16] = f2b(acc[mf][1][j]);
    }
  }
}

// ---- Y[c][t][o] = xconv[c] @ W_t[:128] + W_t[128+nt[c]]; skip unused rows ----
__global__ __launch_bounds__(512) void k_y(const ushort* __restrict__ xconv,
    const ushort* __restrict__ w16y, const ushort* __restrict__ wbias,
    const int* __restrict__ ntype, const uint* __restrict__ bitmap,
    ushort* __restrict__ Y){
  __shared__ ushort As[128*128];    // row*128 + (c16 ^ (row&7))*8
  __shared__ ushort bsh[6272];
  __shared__ int nts[128];
  __shared__ unsigned char usedb[896];
  const int tid = threadIdx.x;
  const int tile = blockIdx.x;

  {
    int row = tid >> 2;
    int c0 = (tid & 3) * 4;
    const ushort* src = xconv + ((size_t)tile*128 + row)*128;
    #pragma unroll
    for (int i=0;i<4;i++){
      int c16 = c0 + i;
      uint4 v = *(const uint4*)(src + c16*8);
      *(uint4*)&As[row*128 + ((c16 ^ (row & 7))*8)] = v;
    }
  }
  for (int i = tid; i < 3136; i += 512) ((uint*)bsh)[i] = ((const uint*)wbias)[i];
  if (tid < 128) nts[tid] = ntype[tile*128 + tid];
  for (int i = tid; i < 896; i += 512){        // FIX: strided fill (block has 512 threads)
    int G = tile*896 + i;                      // tile*896 is 32-aligned (896 = 28*32)
    usedb[i] = (bitmap[G >> 5] >> (G & 31)) & 1u;
  }
  __syncthreads();

  const int w = tid >> 6, l = tid & 63;
  const int mg = w >> 2, nc = w & 3;          // 2 row-groups x 4 col-groups
  const int arow = l & 15, kgrp = l >> 4;
  const int obase = nc*32 + arow;

  for (int t = 0; t < 7; ++t){
    f32x4 acc[4][2];
    #pragma unroll
    for (int mf=0;mf<4;mf++){ acc[mf][0]=(f32x4){0,0,0,0}; acc[mf][1]=(f32x4){0,0,0,0}; }
    const ushort* wt = w16y + t*16384;
    #pragma unroll
    for (int kf = 0; kf < 4; ++kf){
      const int kof = kf*32 + kgrp*8;
      short8 b0 = *(const short8*)(wt + (size_t)obase*128 + kof);
      short8 b1 = *(const short8*)(wt + (size_t)(obase+16)*128 + kof);
      #pragma unroll
      for (int mf = 0; mf < 4; ++mf){
        int row = mg*64 + mf*16 + arow;
        int c16 = (kf*4 + kgrp) ^ (row & 7);
        short8 a = *(const short8*)&As[row*128 + c16*8];
        acc[mf][0] = __builtin_amdgcn_mfma_f32_16x16x32_bf16(a, b0, acc[mf][0], 0,0,0);
        acc[mf][1] = __builtin_amdgcn_mfma_f32_16x16x32_bf16(a, b1, acc[mf][1], 0,0,0);
      }
    }
    #pragma unroll
    for (int mf = 0; mf < 4; ++mf){
      #pragma unroll
      for (int j = 0; j < 4; ++j){
        int rl = mg*64 + mf*16 + (l>>4)*4 + j;
        if (usedb[rl*7 + t]){
          int ntv = nts[rl];
          size_t grow = ((size_t)(tile*128 + rl)*7 + t)*128;
          int bb = (t*7 + ntv)*128;
          Y[grow + obase]      = f2b(acc[mf][0][j] + b2f_lo((uint)bsh[bb + obase]));
          Y[grow + obase + 16] = f2b(acc[mf][1][j] + b2f_lo((uint)bsh[bb + obase + 16]));
        }
      }
    }
  }
}

// ---- out[v] = sum over bucket[v] of Y rows (f32 accum); 16 lanes x uint4 ----
__global__ __launch_bounds__(256) void k_gather(const int* __restrict__ cnt,
    const int* __restrict__ bucket, const ushort* __restrict__ Y, float* __restrict__ out){
  const int tid = threadIdx.x;
  const int slot = tid >> 4, lane = tid & 15;
  const int v = blockIdx.x*16 + slot;
  const int n = min(cnt[v], CAP);
  const int* brow = bucket + (size_t)v*CAP;
  float acc[8] = {0.f,0.f,0.f,0.f,0.f,0.f,0.f,0.f};

  int m[EG]; uint4 d[EG];
  const int nb = min(n, EG);
  #pragma unroll
  for (int i=0;i<EG;i++) if (i < nb) m[i] = brow[i];
  #pragma unroll
  for (int i=0;i<EG;i++) if (i < nb)
    d[i] = *(const uint4*)(Y + (size_t)m[i]*C_IN + lane*8);
  #pragma unroll
  for (int i=0;i<EG;i++){
    if (i < nb){
      acc[0] += b2f_lo(d[i].x); acc[1] += b2f_hi(d[i].x);
      acc[2] += b2f_lo(d[i].y); acc[3] += b2f_hi(d[i].y);
      acc[4] += b2f_lo(d[i].z); acc[5] += b2f_hi(d[i].z);
      acc[6] += b2f_lo(d[i].w); acc[7] += b2f_hi(d[i].w);
    }
  }
  for (int e = EG; e < n; e += 4){
    int n4 = min(n - e, 4);
    int m4[4]; uint4 d4[4];
    #pragma unroll
    for (int i=0;i<4;i++) if (i < n4) m4[i] = brow[e + i];
    #pragma unroll
    for (int i=0;i<4;i++) if (i < n4)
      d4[i] = *(const uint4*)(Y + (size_t)m4[i]*C_IN + lane*8);
    #pragma unroll
    for (int i=0;i<4;i++){
      if (i < n4){
        acc[0] += b2f_lo(d4[i].x); acc[1] += b2f_hi(d4[i].x);
        acc[2] += b2f_lo(d4[i].y); acc[3] += b2f_hi(d4[i].y);
        acc[4] += b2f_lo(d4[i].z); acc[5] += b2f_hi(d4[i].z);
        acc[6] += b2f_lo(d4[i].w); acc[7] += b2f_hi(d4[i].w);
      }
    }
  }
  float4 o0; o0.x=acc[0]; o0.y=acc[1]; o0.z=acc[2]; o0.w=acc[3];
  float4 o1; o1.x=acc[4]; o1.y=acc[5]; o1.z=acc[6]; o1.w=acc[7];
  float* dst = out + (size_t)v*C_IN + lane*8;
  *(float4*)dst = o0;
  *(float4*)(dst + 4) = o1;
}

extern "C" void kernel_launch(void* const* d_in, const int* in_sizes, int n_in,
                              void* d_out, int out_size, void* d_ws, size_t ws_size,
                              hipStream_t stream){
  const float* x     = (const float*)d_in[0];
  const int*   ei    = (const int*)d_in[2];
  const int*   et    = (const int*)d_in[3];
  const int*   nt    = (const int*)d_in[4];
  const float* wdown = (const float*)d_in[5];
  const float* wconv = (const float*)d_in[6];
  float* out = (float*)d_out;

  char* p = (char*)d_ws;
  ushort* xconv = (ushort*)p; p += (size_t)N_CONV*C_IN*2;        // 29.36 MB
  ushort* wd16  = (ushort*)p; p += (size_t)128*1024*2;           // 256 KB
  ushort* w16y  = (ushort*)p; p += (size_t)114688*2;             // 224 KB
  ushort* wbias = (ushort*)p; p += 16384;                        // 16 KB
  int* cnt      = (int*)p;    p += (size_t)N_CONV*4;             // 448 KB
  uint* bitmap  = (uint*)p;   p += 25600*4;                      // 100 KB (zeroed with cnt)
  int* bucket   = (int*)p;    p += (size_t)N_CONV*CAP*4;         // 14.68 MB
  ushort* Y     = (ushort*)p;                                    // 205.5 MB

  k_prep<<<COPY_BLK + PREPW_BLK + ZERO_BLK, 256, 0, stream>>>(x, wconv, wdown, xconv, w16y, wbias, wd16, cnt);
  k_sd<<<DOWN_BLK + SCAT_BLK, 512, 0, stream>>>(ei, et, cnt, bucket, bitmap, x, wd16, xconv);
  k_y<<<N_CONV/128, 512, 0, stream>>>(xconv, w16y, wbias, nt, bitmap, Y);
  k_gather<<<N_CONV/16, 256, 0, stream>>>(cnt, bucket, Y, out);
}

// Round 11
// 289.001 us; speedup vs baseline: 1.1330x; 1.1330x over previous
//
#include <hip/hip_runtime.h>
#include <stdint.h>

#define C_IN 128
#define NUMD 524288
#define LNUMD 32768
#define NNUM_DM1 (LNUMD + NUMD/8)
#define PREFIX 16384
#define N_CONV (PREFIX + NNUM_DM1)   // 114688
#define N_EDGES (N_CONV * 7)         // 802816
#define ND8 (NUMD/8)                 // 65536
#define CAP 32
#define EG 12

#define COPY_BLK ((PREFIX+LNUMD)*32/256)     // 6144
#define PREPW_N (114688 + 6272 + 131072)     // w16y + wbias + wd16 = 252032
#define PREPW_BLK ((PREPW_N + 255)/256)      // 985
#define ZERO_BLK 308                         // cnt (458752B) + used (802816B), int4-strided
#define DOWN_BLK (ND8/128)                   // 512
#define SCAT_BLK (N_EDGES/512)               // 1568

typedef __attribute__((ext_vector_type(8))) short short8;
typedef __attribute__((ext_vector_type(4))) float f32x4;

__device__ inline ushort f2b(float f){
  union { float f; uint32_t u; } v; v.f = f;
  uint32_t r = v.u + 0x7fffu + ((v.u >> 16) & 1u);
  return (ushort)(r >> 16);
}
__device__ inline float b2f_lo(uint32_t u){ union { uint32_t u; float f; } v; v.u = u << 16; return v.f; }
__device__ inline float b2f_hi(uint32_t u){ union { uint32_t u; float f; } v; v.u = u & 0xffff0000u; return v.f; }

#define BAR_LGKM() do { \
    asm volatile("s_waitcnt lgkmcnt(0)" ::: "memory"); \
    __builtin_amdgcn_s_barrier(); \
    asm volatile("" ::: "memory"); \
  } while(0)

// ---- fused: copy prefix+leaf rows | weight conversion | zero cnt+used ----
__global__ void k_prep(const float* __restrict__ x, const float* __restrict__ wconv,
                       const float* __restrict__ wdown,
                       ushort* __restrict__ xconv, ushort* __restrict__ w16y,
                       ushort* __restrict__ wbias, ushort* __restrict__ wd16,
                       int* __restrict__ cnt){
  const int bid = blockIdx.x;
  if (bid < COPY_BLK){
    int gid = bid*256 + threadIdx.x;
    int row = gid >> 5, seg = (gid & 31) * 4;
    int srow, drow;
    if (row < PREFIX){ srow = row; drow = row; }
    else { int k = row - PREFIX; srow = PREFIX + k; drow = PREFIX + 3*k; }
    const float4 f = *(const float4*)(x + (size_t)srow*C_IN + seg);
    ushort4 o; o.x=f2b(f.x); o.y=f2b(f.y); o.z=f2b(f.z); o.w=f2b(f.w);
    *(ushort4*)(xconv + (size_t)drow*C_IN + seg) = o;
  } else if (bid < COPY_BLK + PREPW_BLK){
    int gid = (bid - COPY_BLK)*256 + threadIdx.x;
    if (gid < 114688){
      // w16y[t][o][k] = wconv[(t*135+k)*128 + o]
      int t = gid >> 14, rem = gid & 16383;
      int o = rem >> 7, k = rem & 127;
      w16y[gid] = f2b(wconv[(size_t)(t*135 + k)*128 + o]);
    } else if (gid < 120960){
      // wbias[t][n][o] = wconv[(t*135+128+n)*128 + o]
      int q = gid - 114688;
      int t = q / 896, rem = q % 896;
      int n = rem >> 7, o = rem & 127;
      wbias[q] = f2b(wconv[(size_t)(t*135 + 128 + n)*128 + o]);
    } else if (gid < PREPW_N){
      int i = gid - 120960;
      wd16[i] = f2b(wdown[i]);
    }
  } else {
    // zero cnt[114688 ints] + used[802816 bytes] (contiguous)
    int gid = (bid - COPY_BLK - PREPW_BLK)*256 + threadIdx.x;
    int4 z = {0,0,0,0};
    *(int4*)(cnt + gid*4) = z;
  }
}

// ---- fused: down-projection GEMM (128-row tile, K-chunked, pinned pipeline) | scatter ----
__global__ __launch_bounds__(512) void k_sd(const int* __restrict__ ei, const int* __restrict__ et,
    int* __restrict__ cnt, int* __restrict__ bucket, unsigned char* __restrict__ used,
    const float* __restrict__ x, const ushort* __restrict__ wd16, ushort* __restrict__ xconv){
  const int bid = blockIdx.x;
  if (bid >= DOWN_BLK){
    int e = (bid - DOWN_BLK)*512 + threadIdx.x;
    int r = ei[e], c = ei[N_EDGES + e], t = et[e];
    int key = c*7 + t;
    int pos = atomicAdd(&cnt[r], 1);
    if (pos < CAP) bucket[r*CAP + pos] = key;
    used[key] = 1;                              // plain store: no RMW contention
    return;
  }
  __shared__ ushort As[128*128];      // row*128 + (slot ^ ((row&7)<<1))*8
  const int tid = threadIdx.x;
  const int n0 = bid * 128;
  const float* xd = x + (size_t)(PREFIX+LNUMD)*C_IN;

  const int srow = tid >> 2, kbase = (tid & 3) * 32;
  const float* src = xd + (size_t)(n0+srow)*1024 + kbase;

  const int w = tid >> 6, l = tid & 63;
  const int mg = w >> 2, nc = w & 3;            // 2 row-groups x 4 col-groups
  const int arow = l & 15, kgrp = l >> 4;
  const int obase = nc*32 + arow;

  f32x4 acc[4][2];
  #pragma unroll
  for (int mf=0;mf<4;mf++){ acc[mf][0]=(f32x4){0,0,0,0}; acc[mf][1]=(f32x4){0,0,0,0}; }

  float4 pf[8];
  #pragma unroll
  for (int i=0;i<8;i++) pf[i] = *(const float4*)(src + i*4);

  for (int c = 0; c < 8; ++c){
    // pack prefetched A -> LDS (swizzled)
    #pragma unroll
    for (int i=0;i<4;i++){
      uint4 pk;
      pk.x = (uint)f2b(pf[2*i].x)   | ((uint)f2b(pf[2*i].y)<<16);
      pk.y = (uint)f2b(pf[2*i].z)   | ((uint)f2b(pf[2*i].w)<<16);
      pk.z = (uint)f2b(pf[2*i+1].x) | ((uint)f2b(pf[2*i+1].y)<<16);
      pk.w = (uint)f2b(pf[2*i+1].z) | ((uint)f2b(pf[2*i+1].w)<<16);
      int slot = (kbase >> 3) + i;
      *(uint4*)&As[srow*128 + ((slot ^ ((srow & 7) << 1)) << 3)] = pk;
    }
    BAR_LGKM();                                 // LDS visible; vmcnt untouched

    // B fragments for this chunk (oldest in vmcnt FIFO, L2-hot)
    short8 breg[8];
    #pragma unroll
    for (int kf=0;kf<4;kf++){
      const ushort* bp = wd16 + c*128 + kf*32 + kgrp*8;
      breg[kf*2]   = *(const short8*)(bp + (size_t)obase*1024);
      breg[kf*2+1] = *(const short8*)(bp + (size_t)(obase+16)*1024);
    }
    __builtin_amdgcn_sched_barrier(0);          // pin: B issued before A-prefetch
    // next chunk's A prefetch (youngest: stays in flight over MFMA)
    if (c < 7){
      const float* s2 = src + (c+1)*128;
      #pragma unroll
      for (int i=0;i<8;i++) pf[i] = *(const float4*)(s2 + i*4);
    }
    __builtin_amdgcn_sched_barrier(0);          // pin: prefetch issued before MFMA waits

    // MFMA from LDS A + reg B (B-wait = vmcnt(8): A-prefetch stays outstanding)
    #pragma unroll
    for (int kf=0;kf<4;kf++){
      #pragma unroll
      for (int mf=0;mf<4;mf++){
        int row = mg*64 + mf*16 + arow;
        int slot = (kf*4 + kgrp) ^ ((arow & 7) << 1);
        short8 a = *(const short8*)&As[row*128 + (slot << 3)];
        acc[mf][0] = __builtin_amdgcn_mfma_f32_16x16x32_bf16(a, breg[kf*2],   acc[mf][0], 0,0,0);
        acc[mf][1] = __builtin_amdgcn_mfma_f32_16x16x32_bf16(a, breg[kf*2+1], acc[mf][1], 0,0,0);
      }
    }
    BAR_LGKM();                                 // protect As before next ds_write
  }

  #pragma unroll
  for (int mf = 0; mf < 4; ++mf){
    #pragma unroll
    for (int j = 0; j < 4; ++j){
      int rl = mg*64 + mf*16 + (l>>4)*4 + j;
      int n = n0 + rl;
      int i = 3*(n>>1) + 1 + (n&1);
      ushort* dst = xconv + (size_t)(PREFIX + i)*C_IN;
      dst[obase]      = f2b(acc[mf][0][j]);
      dst[obase + 16] = f2b(acc[mf][1][j]);
    }
  }
}

// ---- Y[c][t][o] = xconv[c] @ W_t[:128] + W_t[128+nt[c]]; skip unused rows ----
__global__ __launch_bounds__(512) void k_y(const ushort* __restrict__ xconv,
    const ushort* __restrict__ w16y, const ushort* __restrict__ wbias,
    const int* __restrict__ ntype, const unsigned char* __restrict__ used,
    ushort* __restrict__ Y){
  __shared__ ushort As[128*128];    // row*128 + (c16 ^ (row&7))*8
  __shared__ ushort bsh[6272];
  __shared__ int nts[128];
  __shared__ uint usedw[224];
  const int tid = threadIdx.x;
  const int tile = blockIdx.x;
  const unsigned char* usedb = (const unsigned char*)usedw;

  {
    int row = tid >> 2;
    int c0 = (tid & 3) * 4;
    const ushort* src = xconv + ((size_t)tile*128 + row)*128;
    #pragma unroll
    for (int i=0;i<4;i++){
      int c16 = c0 + i;
      uint4 v = *(const uint4*)(src + c16*8);
      *(uint4*)&As[row*128 + ((c16 ^ (row & 7))*8)] = v;
    }
  }
  for (int i = tid; i < 3136; i += 512) ((uint*)bsh)[i] = ((const uint*)wbias)[i];
  if (tid < 128) nts[tid] = ntype[tile*128 + tid];
  if (tid < 224) usedw[tid] = ((const uint*)(used + (size_t)tile*896))[tid];
  __syncthreads();

  const int w = tid >> 6, l = tid & 63;
  const int mg = w >> 2, nc = w & 3;          // 2 row-groups x 4 col-groups
  const int arow = l & 15, kgrp = l >> 4;
  const int obase = nc*32 + arow;

  for (int t = 0; t < 7; ++t){
    f32x4 acc[4][2];
    #pragma unroll
    for (int mf=0;mf<4;mf++){ acc[mf][0]=(f32x4){0,0,0,0}; acc[mf][1]=(f32x4){0,0,0,0}; }
    const ushort* wt = w16y + t*16384;
    #pragma unroll
    for (int kf = 0; kf < 4; ++kf){
      const int kof = kf*32 + kgrp*8;
      short8 b0 = *(const short8*)(wt + (size_t)obase*128 + kof);
      short8 b1 = *(const short8*)(wt + (size_t)(obase+16)*128 + kof);
      #pragma unroll
      for (int mf = 0; mf < 4; ++mf){
        int row = mg*64 + mf*16 + arow;
        int c16 = (kf*4 + kgrp) ^ (row & 7);
        short8 a = *(const short8*)&As[row*128 + c16*8];
        acc[mf][0] = __builtin_amdgcn_mfma_f32_16x16x32_bf16(a, b0, acc[mf][0], 0,0,0);
        acc[mf][1] = __builtin_amdgcn_mfma_f32_16x16x32_bf16(a, b1, acc[mf][1], 0,0,0);
      }
    }
    #pragma unroll
    for (int mf = 0; mf < 4; ++mf){
      #pragma unroll
      for (int j = 0; j < 4; ++j){
        int rl = mg*64 + mf*16 + (l>>4)*4 + j;
        if (usedb[rl*7 + t]){
          int ntv = nts[rl];
          size_t grow = ((size_t)(tile*128 + rl)*7 + t)*128;
          int bb = (t*7 + ntv)*128;
          Y[grow + obase]      = f2b(acc[mf][0][j] + b2f_lo((uint)bsh[bb + obase]));
          Y[grow + obase + 16] = f2b(acc[mf][1][j] + b2f_lo((uint)bsh[bb + obase + 16]));
        }
      }
    }
  }
}

// ---- out[v] = sum over bucket[v] of Y rows (f32 accum); 16 lanes x uint4 ----
__global__ __launch_bounds__(256) void k_gather(const int* __restrict__ cnt,
    const int* __restrict__ bucket, const ushort* __restrict__ Y, float* __restrict__ out){
  const int tid = threadIdx.x;
  const int slot = tid >> 4, lane = tid & 15;
  const int v = blockIdx.x*16 + slot;
  const int n = min(cnt[v], CAP);
  const int* brow = bucket + (size_t)v*CAP;
  float acc[8] = {0.f,0.f,0.f,0.f,0.f,0.f,0.f,0.f};

  int m[EG]; uint4 d[EG];
  const int nb = min(n, EG);
  #pragma unroll
  for (int i=0;i<EG;i++) if (i < nb) m[i] = brow[i];
  #pragma unroll
  for (int i=0;i<EG;i++) if (i < nb)
    d[i] = *(const uint4*)(Y + (size_t)m[i]*C_IN + lane*8);
  #pragma unroll
  for (int i=0;i<EG;i++){
    if (i < nb){
      acc[0] += b2f_lo(d[i].x); acc[1] += b2f_hi(d[i].x);
      acc[2] += b2f_lo(d[i].y); acc[3] += b2f_hi(d[i].y);
      acc[4] += b2f_lo(d[i].z); acc[5] += b2f_hi(d[i].z);
      acc[6] += b2f_lo(d[i].w); acc[7] += b2f_hi(d[i].w);
    }
  }
  for (int e = EG; e < n; e += 4){
    int n4 = min(n - e, 4);
    int m4[4]; uint4 d4[4];
    #pragma unroll
    for (int i=0;i<4;i++) if (i < n4) m4[i] = brow[e + i];
    #pragma unroll
    for (int i=0;i<4;i++) if (i < n4)
      d4[i] = *(const uint4*)(Y + (size_t)m4[i]*C_IN + lane*8);
    #pragma unroll
    for (int i=0;i<4;i++){
      if (i < n4){
        acc[0] += b2f_lo(d4[i].x); acc[1] += b2f_hi(d4[i].x);
        acc[2] += b2f_lo(d4[i].y); acc[3] += b2f_hi(d4[i].y);
        acc[4] += b2f_lo(d4[i].z); acc[5] += b2f_hi(d4[i].z);
        acc[6] += b2f_lo(d4[i].w); acc[7] += b2f_hi(d4[i].w);
      }
    }
  }
  float4 o0; o0.x=acc[0]; o0.y=acc[1]; o0.z=acc[2]; o0.w=acc[3];
  float4 o1; o1.x=acc[4]; o1.y=acc[5]; o1.z=acc[6]; o1.w=acc[7];
  float* dst = out + (size_t)v*C_IN + lane*8;
  *(float4*)dst = o0;
  *(float4*)(dst + 4) = o1;
}

extern "C" void kernel_launch(void* const* d_in, const int* in_sizes, int n_in,
                              void* d_out, int out_size, void* d_ws, size_t ws_size,
                              hipStream_t stream){
  const float* x     = (const float*)d_in[0];
  const int*   ei    = (const int*)d_in[2];
  const int*   et    = (const int*)d_in[3];
  const int*   nt    = (const int*)d_in[4];
  const float* wdown = (const float*)d_in[5];
  const float* wconv = (const float*)d_in[6];
  float* out = (float*)d_out;

  char* p = (char*)d_ws;
  ushort* xconv = (ushort*)p; p += (size_t)N_CONV*C_IN*2;        // 29.36 MB
  ushort* wd16  = (ushort*)p; p += (size_t)128*1024*2;           // 256 KB
  ushort* w16y  = (ushort*)p; p += (size_t)114688*2;             // 224 KB
  ushort* wbias = (ushort*)p; p += 16384;                        // 16 KB
  int* cnt      = (int*)p;    p += (size_t)N_CONV*4;             // 448 KB
  unsigned char* used = (unsigned char*)p; p += 802816;          // 784 KB (zeroed with cnt)
  int* bucket   = (int*)p;    p += (size_t)N_CONV*CAP*4;         // 14.68 MB
  ushort* Y     = (ushort*)p;                                    // 205.5 MB

  k_prep<<<COPY_BLK + PREPW_BLK + ZERO_BLK, 256, 0, stream>>>(x, wconv, wdown, xconv, w16y, wbias, wd16, cnt);
  k_sd<<<DOWN_BLK + SCAT_BLK, 512, 0, stream>>>(ei, et, cnt, bucket, used, x, wd16, xconv);
  k_y<<<N_CONV/128, 512, 0, stream>>>(xconv, w16y, wbias, nt, used, Y);
  k_gather<<<N_CONV/16, 256, 0, stream>>>(cnt, bucket, Y, out);
}